// Round 5
// baseline (3018.797 us; speedup 1.0000x reference)
//
#include <hip/hip_runtime.h>
#include <math.h>

#define S 32
#define T 32
#define B 64
#define H 256
#define MSZ 65536   // elements per swizzled bf16 matrix [8 kt][256 col][32 kk]
#define ROWSP 16
#define FPAD 16     // ints per flag slot (64 B line)

typedef __attribute__((ext_vector_type(8))) short s16x8;
typedef __attribute__((ext_vector_type(4))) float f32x4;

__device__ inline unsigned short f2b(float f){
    unsigned u = __builtin_bit_cast(unsigned, f);
    u += 0x7fffu + ((u >> 16) & 1u);          // RNE
    return (unsigned short)(u >> 16);
}
__device__ inline float b2f(unsigned short s){
    unsigned u = ((unsigned)s) << 16;
    return __builtin_bit_cast(float, u);
}
__device__ inline float tanh_fast(float x){
    float e = __builtin_amdgcn_exp2f(x * 2.8853900817779268f);
    float r = __builtin_amdgcn_rcpf(e + 1.0f);
    return fmaf(-2.0f, r, 1.0f);
}
__device__ inline void pollge(int* f, int target){
    while (__hip_atomic_load(f, __ATOMIC_RELAXED, __HIP_MEMORY_SCOPE_AGENT) < target)
        __builtin_amdgcn_s_sleep(1);
}
// A fragment for mfma_f32_16x16x32_bf16 from row-major f32: lane holds A[arow][k0..k0+7]
__device__ inline s16x8 make_afrag(const float* __restrict__ M, int arow, int k0){
    const float* p = M + arow * H + k0;
    float4 x = *(const float4*)(p);
    float4 y = *(const float4*)(p + 4);
    s16x8 r;
    r[0]=(short)f2b(x.x); r[1]=(short)f2b(x.y); r[2]=(short)f2b(x.z); r[3]=(short)f2b(x.w);
    r[4]=(short)f2b(y.x); r[5]=(short)f2b(y.y); r[6]=(short)f2b(y.z); r[7]=(short)f2b(y.w);
    return r;
}

// ---------------- prep: swizzle U (both depths, top/left) + W[1] to bf16 ----
// Bsw[m][kt][c][kk] = M_m[kt*32+kk][c];  m: 0=U0t 1=U0l 2=U1t 3=U1l 4=W1
__global__ __launch_bounds__(256) void prep_kernel(
    const float* __restrict__ U, const float* __restrict__ W,
    unsigned short* __restrict__ Bsw)
{
    int t = blockIdx.x * 256 + threadIdx.x;
    if (t >= 5 * MSZ) return;
    int m  = t >> 16;
    int r  = t & 65535;
    int kt = r >> 13;
    int r2 = r & 8191;
    int c  = r2 >> 5;
    int kk = r2 & 31;
    int krow = kt * 32 + kk;
    float v;
    if (m < 4){ int d = m >> 1, ope = m & 1; v = U[((size_t)d*2*H + ope*H + krow)*H + c]; }
    else      { v = W[((size_t)H + krow)*H + c]; }   // W[1]
    Bsw[t] = f2b(v);
}

// ---------------- depth-0 projections (bf16 out): sxw = src@W0, tyw = trg@W0
__global__ __launch_bounds__(256) void proj0b_kernel(
    const float* __restrict__ src, const float* __restrict__ trg,
    const float* __restrict__ W0, unsigned short* __restrict__ sxw,
    unsigned short* __restrict__ tyw)
{
    const int c = threadIdx.x;
    int gr0 = blockIdx.x * ROWSP;
    const float* inp; unsigned short* outp; int r0;
    if (gr0 < S * B) { inp = src; outp = sxw; r0 = gr0; }
    else             { inp = trg; outp = tyw; r0 = gr0 - S * B; }

    float acc[ROWSP];
#pragma unroll
    for (int rr = 0; rr < ROWSP; ++rr) acc[rr] = 0.f;
    for (int k = 0; k < H; ++k) {
        float wv = W0[k * H + c];
#pragma unroll
        for (int rr = 0; rr < ROWSP; ++rr)
            acc[rr] = fmaf(inp[(size_t)(r0 + rr) * H + k], wv, acc[rr]);
    }
#pragma unroll
    for (int rr = 0; rr < ROWSP; ++rr)
        outp[(size_t)(r0 + rr) * H + c] = f2b(acc[rr]);
}

__global__ __launch_bounds__(256) void zeroflags_kernel(int* flags, int n){
    int t = blockIdx.x * 256 + threadIdx.x;
    if (t < n) flags[t] = 0;
}

// ---------------- persistent dataflow: one block per (depth,row) ----------
// 64 blocks x 1024 threads. blk 0..31 = depth0 row i, 32..63 = depth1 row i.
// Left dependency is internal (persistent LDS). Cross-block: top flag only
// (+ f0 cross-depth for d1, which has slack). Single flag/cell, target 1.
__global__ __launch_bounds__(1024, 4) void grid_kernel(
    const unsigned short* __restrict__ Bsw,
    const unsigned short* __restrict__ sxwb,
    const unsigned short* __restrict__ tywb,
    const float* __restrict__ bvec,
    float* __restrict__ out,
    int* __restrict__ flags)
{
    __shared__ char lds[65536];   // [0,32K) left hx persist (R0); [32K,64K) top staging (R1)

    const int blk   = blockIdx.x;
    const int depth = blk >> 5;
    const int i     = blk & 31;

    const int tid  = threadIdx.x;
    const int lane = tid & 63;
    const int wv   = tid >> 6;          // wave 0..15, owns 16 cols
    const int colq = lane & 15;
    const int hi   = lane >> 4;
    const int kk0  = hi * 8;
    const int col  = wv * 16 + colq;
    const int hi16 = hi * 16;
    const int lswz = (colq & 7) << 4;   // A-frag read swizzle (A-row&7 == colq&7)

    const int srow = tid >> 4;          // staging row 0..63
    const int sg   = tid & 15;          // granule-pair index
    const int k0s  = sg * 16;           // k base (16 floats per thread)
    const int swzS = (srow & 7) << 4;

    int* f0 = flags;
    int* f1 = flags + S*T*FPAD;

    const size_t CH_ = (size_t)B * H;
#define OPTR(dd,ii,jj,cc) (out + ((((size_t)(dd)*S + (ii))*T + (jj))*2 + (cc)) * CH_)

// stage 64x256 f32 matrix M -> bf16 LDS at BASE, row stride 512B, XOR-swizzled
#define STAGE(BASE, M) do { \
    const float* _p = (M) + (size_t)srow * H + k0s; \
    float4 _a = *(const float4*)(_p),   _b = *(const float4*)(_p+4); \
    float4 _c = *(const float4*)(_p+8), _d = *(const float4*)(_p+12); \
    uint4 _g0, _g1; \
    _g0.x = f2b(_a.x) | ((unsigned)f2b(_a.y)<<16); _g0.y = f2b(_a.z) | ((unsigned)f2b(_a.w)<<16); \
    _g0.z = f2b(_b.x) | ((unsigned)f2b(_b.y)<<16); _g0.w = f2b(_b.z) | ((unsigned)f2b(_b.w)<<16); \
    _g1.x = f2b(_c.x) | ((unsigned)f2b(_c.y)<<16); _g1.y = f2b(_c.z) | ((unsigned)f2b(_c.w)<<16); \
    _g1.z = f2b(_d.x) | ((unsigned)f2b(_d.y)<<16); _g1.w = f2b(_d.z) | ((unsigned)f2b(_d.w)<<16); \
    *(uint4*)(lds + (BASE) + srow*512 + ((sg*32)      ^ swzS)) = _g0; \
    *(uint4*)(lds + (BASE) + srow*512 + ((sg*32 + 16) ^ swzS)) = _g1; \
} while(0)

#define AFRAG(BASE, RT, KT) (*(const s16x8*)(lds + (BASE) + ((RT)*16 + colq)*512 + ((((KT)*64) + hi16) ^ lswz)))

    if (depth == 0) {
        s16x8 bfT[8], bfL[8];
#pragma unroll
        for (int kt = 0; kt < 8; ++kt) {
            int o = (kt * H + col) * 32 + kk0;
            bfT[kt] = *(const s16x8*)(Bsw + o);
            bfL[kt] = *(const s16x8*)(Bsw + (size_t)MSZ + o);
        }
        const float bb = bvec[col];
        unsigned short xwr[16];
        {
            const unsigned short* xwp = sxwb + (size_t)i * CH_;
#pragma unroll
            for (int rt = 0; rt < 4; ++rt)
#pragma unroll
                for (int q = 0; q < 4; ++q)
                    xwr[rt*4+q] = xwp[(size_t)(rt*16 + hi*4 + q) * H + col];
        }

        for (int j = 0; j < T; ++j) {
            unsigned short ywr[16];
            {
                const unsigned short* ywp = tywb + (size_t)j * CH_;
#pragma unroll
                for (int rt = 0; rt < 4; ++rt)
#pragma unroll
                    for (int q = 0; q < 4; ++q)
                        ywr[rt*4+q] = ywp[(size_t)(rt*16 + hi*4 + q) * H + col];
            }
            f32x4 acc[4];
#pragma unroll
            for (int rt = 0; rt < 4; ++rt) acc[rt] = (f32x4)(0.f);

            if (j > 0) {   // left matmul from persistent LDS (own previous hx)
#pragma unroll
                for (int kt = 0; kt < 8; ++kt)
#pragma unroll
                    for (int rt = 0; rt < 4; ++rt)
                        acc[rt] = __builtin_amdgcn_mfma_f32_16x16x32_bf16(AFRAG(0, rt, kt), bfL[kt], acc[rt], 0, 0, 0);
            }
            __syncthreads();                       // R0 reads done before epilogue writes

            if (i > 0) {
                if (tid == 0) pollge(&f0[((i-1)*T + j)*FPAD], 1);
                __syncthreads();
                STAGE(32768, OPTR(0, i-1, j, 0));
                __syncthreads();
#pragma unroll
                for (int kt = 0; kt < 8; ++kt)
#pragma unroll
                    for (int rt = 0; rt < 4; ++rt)
                        acc[rt] = __builtin_amdgcn_mfma_f32_16x16x32_bf16(AFRAG(32768, rt, kt), bfT[kt], acc[rt], 0, 0, 0);
            }

            float* ox = OPTR(0, i, j, 0);
            float* oy = OPTR(0, i, j, 1);
#pragma unroll
            for (int rt = 0; rt < 4; ++rt)
#pragma unroll
                for (int q = 0; q < 4; ++q) {
                    int idx = rt*4+q;
                    int r = rt*16 + hi*4 + q;
                    float rec = acc[rt][q] + bb;
                    float hx = tanh_fast(b2f(xwr[idx]) + rec);
                    float hy = tanh_fast(b2f(ywr[idx]) + rec);
                    __hip_atomic_store(&ox[r*H + col], hx, __ATOMIC_RELAXED, __HIP_MEMORY_SCOPE_AGENT);
                    __hip_atomic_store(&oy[r*H + col], hy, __ATOMIC_RELAXED, __HIP_MEMORY_SCOPE_AGENT);
                    *(unsigned short*)(lds + r*512 + ((col*2) ^ ((r&7)<<4))) = f2b(hx);
                }
            asm volatile("s_waitcnt vmcnt(0)" ::: "memory");
            __syncthreads();
            if (tid == 0)
                __hip_atomic_store(&f0[(i*T + j)*FPAD], 1, __ATOMIC_RELAXED, __HIP_MEMORY_SCOPE_AGENT);
        }
    } else {
        const float bb = bvec[H + col];

        for (int j = 0; j < T; ++j) {
            // opaque base: prevents LICM hoisting the streamed B-frags (VGPR blowup)
            uintptr_t bsw_o = (uintptr_t)Bsw;
            asm volatile("" : "+v"(bsw_o));
            const unsigned short* mT = (const unsigned short*)bsw_o + (size_t)2*MSZ;
            const unsigned short* mL = (const unsigned short*)bsw_o + (size_t)3*MSZ;
            const unsigned short* mW = (const unsigned short*)bsw_o + (size_t)4*MSZ;

            f32x4 ar[4], ax[4], ay[4];
#pragma unroll
            for (int rt = 0; rt < 4; ++rt){ ar[rt]=(f32x4)(0.f); ax[rt]=(f32x4)(0.f); ay[rt]=(f32x4)(0.f); }

            if (j > 0) {   // left matmul from persistent LDS, streamed bL
#pragma unroll
                for (int kt = 0; kt < 8; ++kt) {
                    s16x8 bL = *(const s16x8*)(mL + (kt * H + col) * 32 + kk0);
#pragma unroll
                    for (int rt = 0; rt < 4; ++rt)
                        ar[rt] = __builtin_amdgcn_mfma_f32_16x16x32_bf16(AFRAG(0, rt, kt), bL, ar[rt], 0, 0, 0);
                }
            }
            __syncthreads();                       // R0 reads done

            if (tid == 0) pollge(&f0[(i*T + j)*FPAD], 1);
            __syncthreads();
            const float* hx0 = OPTR(0, i, j, 0);
            const float* hy0 = OPTR(0, i, j, 1);
#pragma unroll
            for (int kt = 0; kt < 8; ++kt) {
                s16x8 bW = *(const s16x8*)(mW + (kt * H + col) * 32 + kk0);
                const int k0 = kt*32 + kk0;
#pragma unroll
                for (int rt = 0; rt < 4; ++rt) {
                    ax[rt] = __builtin_amdgcn_mfma_f32_16x16x32_bf16(make_afrag(hx0, rt*16 + colq, k0), bW, ax[rt], 0, 0, 0);
                    ay[rt] = __builtin_amdgcn_mfma_f32_16x16x32_bf16(make_afrag(hy0, rt*16 + colq, k0), bW, ay[rt], 0, 0, 0);
                }
            }

            if (i > 0) {
                if (tid == 0) pollge(&f1[((i-1)*T + j)*FPAD], 1);
                __syncthreads();
                STAGE(32768, OPTR(1, i-1, j, 0));
                __syncthreads();
#pragma unroll
                for (int kt = 0; kt < 8; ++kt) {
                    s16x8 bT = *(const s16x8*)(mT + (kt * H + col) * 32 + kk0);
#pragma unroll
                    for (int rt = 0; rt < 4; ++rt)
                        ar[rt] = __builtin_amdgcn_mfma_f32_16x16x32_bf16(AFRAG(32768, rt, kt), bT, ar[rt], 0, 0, 0);
                }
            }

            float* ox = OPTR(1, i, j, 0);
            float* oy = OPTR(1, i, j, 1);
#pragma unroll
            for (int rt = 0; rt < 4; ++rt)
#pragma unroll
                for (int q = 0; q < 4; ++q) {
                    int r = rt*16 + hi*4 + q;
                    float rec = ar[rt][q] + bb;
                    float hx = tanh_fast(ax[rt][q] + rec);
                    float hy = tanh_fast(ay[rt][q] + rec);
                    __hip_atomic_store(&ox[r*H + col], hx, __ATOMIC_RELAXED, __HIP_MEMORY_SCOPE_AGENT);
                    __hip_atomic_store(&oy[r*H + col], hy, __ATOMIC_RELAXED, __HIP_MEMORY_SCOPE_AGENT);
                    *(unsigned short*)(lds + r*512 + ((col*2) ^ ((r&7)<<4))) = f2b(hx);
                }
            asm volatile("s_waitcnt vmcnt(0)" ::: "memory");
            __syncthreads();
            if (tid == 0)
                __hip_atomic_store(&f1[(i*T + j)*FPAD], 1, __ATOMIC_RELAXED, __HIP_MEMORY_SCOPE_AGENT);
        }
    }
#undef OPTR
#undef STAGE
#undef AFRAG
}

// =================== staged fallback (round-2 structure) ===================
__global__ __launch_bounds__(64) void stage_kernel(
    const unsigned short* __restrict__ Bsw,
    const unsigned short* __restrict__ sxwb,
    const unsigned short* __restrict__ tywb,
    const float* __restrict__ bvec,
    float* __restrict__ out, int v)
{
    const int lane = threadIdx.x;
    const int cellid = blockIdx.x >> 2;
    const int stripe = blockIdx.x & 3;

    int ilo0 = (v > T-1) ? v-(T-1) : 0, ihi0 = (v < S-1) ? v : S-1;
    int n0 = (v <= S+T-2) ? (ihi0 - ilo0 + 1) : 0;
    if (n0 < 0) n0 = 0;
    int w1 = v - 1;
    int ilo1 = (w1 > T-1) ? w1-(T-1) : 0;

    int d, i, j;
    if (cellid < n0) { d = 0; i = ilo0 + cellid; j = v - i; }
    else             { d = 1; int q = cellid - n0; i = ilo1 + q; j = w1 - i; }

    const int r0   = stripe * 16;
    const int arow = r0 + (lane & 15);
    const int kk0  = (lane >> 4) * 8;
    const int colq = lane & 15;
    const int rowq = r0 + ((lane >> 4) << 2);

#define OUTB(dd,ii,jj,cc) (out + ((((size_t)(dd)*S + (ii))*T + (jj))*2 + (cc)) * (size_t)(B*H))

    if (d == 0) {
        f32x4 acc[16];
#pragma unroll
        for (int t = 0; t < 16; ++t) acc[t] = (f32x4)(0.f);
        if (i > 0) {
            const float* topM = OUTB(0, i-1, j, 0);
            const unsigned short* Bt = Bsw + 0*MSZ;
            for (int kt = 0; kt < 8; ++kt) {
                s16x8 a = make_afrag(topM, arow, kt*32 + kk0);
                const unsigned short* bp = Bt + (kt*H + colq)*32 + kk0;
#pragma unroll
                for (int ct = 0; ct < 16; ++ct)
                    acc[ct] = __builtin_amdgcn_mfma_f32_16x16x32_bf16(a, *(const s16x8*)(bp + ct*512), acc[ct], 0, 0, 0);
            }
        }
        if (j > 0) {
            const float* lftM = OUTB(0, i, j-1, 0);
            const unsigned short* Bl = Bsw + 1*MSZ;
            for (int kt = 0; kt < 8; ++kt) {
                s16x8 a = make_afrag(lftM, arow, kt*32 + kk0);
                const unsigned short* bp = Bl + (kt*H + colq)*32 + kk0;
#pragma unroll
                for (int ct = 0; ct < 16; ++ct)
                    acc[ct] = __builtin_amdgcn_mfma_f32_16x16x32_bf16(a, *(const s16x8*)(bp + ct*512), acc[ct], 0, 0, 0);
            }
        }
        const unsigned short* xwp = sxwb + (size_t)i * B * H;
        const unsigned short* ywp = tywb + (size_t)j * B * H;
        float* ox = OUTB(0, i, j, 0);
        float* oy = OUTB(0, i, j, 1);
#pragma unroll
        for (int ct = 0; ct < 16; ++ct) {
            int col = ct*16 + colq;
            float bc = bvec[col];
#pragma unroll
            for (int q = 0; q < 4; ++q) {
                int row = rowq + q;
                float rec = acc[ct][q] + bc;
                ox[row*H + col] = tanh_fast(b2f(xwp[row*H + col]) + rec);
                oy[row*H + col] = tanh_fast(b2f(ywp[row*H + col]) + rec);
            }
        }
    } else {
        const float* hx0 = OUTB(0, i, j, 0);
        const float* hy0 = OUTB(0, i, j, 1);
        const float* topM = (i > 0) ? OUTB(1, i-1, j, 0) : (const float*)0;
        const float* lftM = (j > 0) ? OUTB(1, i, j-1, 0) : (const float*)0;
        const unsigned short* BU1t = Bsw + 2*MSZ;
        const unsigned short* BU1l = Bsw + 3*MSZ;
        const unsigned short* BW1  = Bsw + 4*MSZ;
        float* ox = OUTB(1, i, j, 0);
        float* oy = OUTB(1, i, j, 1);

        for (int halfc = 0; halfc < 2; ++halfc) {
            f32x4 arr[8], axx[8], ayy[8];
#pragma unroll
            for (int t = 0; t < 8; ++t) { arr[t]=(f32x4)(0.f); axx[t]=(f32x4)(0.f); ayy[t]=(f32x4)(0.f); }
            const int bbase = halfc*4096 + colq*32 + kk0;

            for (int kt = 0; kt < 8; ++kt) {
                const int k0 = kt*32 + kk0;
                const int bofs = kt*H*32 + bbase;
                if (topM) {
                    s16x8 a = make_afrag(topM, arow, k0);
#pragma unroll
                    for (int ct = 0; ct < 8; ++ct)
                        arr[ct] = __builtin_amdgcn_mfma_f32_16x16x32_bf16(a, *(const s16x8*)(BU1t + bofs + ct*512), arr[ct], 0, 0, 0);
                }
                if (lftM) {
                    s16x8 a = make_afrag(lftM, arow, k0);
#pragma unroll
                    for (int ct = 0; ct < 8; ++ct)
                        arr[ct] = __builtin_amdgcn_mfma_f32_16x16x32_bf16(a, *(const s16x8*)(BU1l + bofs + ct*512), arr[ct], 0, 0, 0);
                }
                {
                    s16x8 a = make_afrag(hx0, arow, k0);
#pragma unroll
                    for (int ct = 0; ct < 8; ++ct)
                        axx[ct] = __builtin_amdgcn_mfma_f32_16x16x32_bf16(a, *(const s16x8*)(BW1 + bofs + ct*512), axx[ct], 0, 0, 0);
                }
                {
                    s16x8 a = make_afrag(hy0, arow, k0);
#pragma unroll
                    for (int ct = 0; ct < 8; ++ct)
                        ayy[ct] = __builtin_amdgcn_mfma_f32_16x16x32_bf16(a, *(const s16x8*)(BW1 + bofs + ct*512), ayy[ct], 0, 0, 0);
                }
            }
#pragma unroll
            for (int ct = 0; ct < 8; ++ct) {
                int col = halfc*128 + ct*16 + colq;
                float bc = bvec[H + col];
#pragma unroll
                for (int q = 0; q < 4; ++q) {
                    int row = rowq + q;
                    float rec = arr[ct][q] + bc;
                    ox[row*H + col] = tanh_fast(axx[ct][q] + rec);
                    oy[row*H + col] = tanh_fast(ayy[ct][q] + rec);
                }
            }
        }
    }
#undef OUTB
}

// ============================ host launcher ================================
extern "C" void kernel_launch(void* const* d_in, const int* in_sizes, int n_in,
                              void* d_out, int out_size, void* d_ws, size_t ws_size,
                              hipStream_t stream)
{
    const float* src = (const float*)d_in[0];
    const float* trg = (const float*)d_in[1];
    const float* W   = (const float*)d_in[2];
    const float* U   = (const float*)d_in[3];
    const float* b   = (const float*)d_in[4];
    float* out = (float*)d_out;

    const int nflags = 2 * S * T * FPAD;
    const size_t need_stage   = (size_t)5*MSZ*2 + (size_t)2*S*B*H*2;
    const size_t need_persist = need_stage + (size_t)nflags*sizeof(int);

    unsigned short* Bsw  = (unsigned short*)d_ws;
    unsigned short* sxwb = Bsw + (size_t)5*MSZ;
    unsigned short* tywb = sxwb + (size_t)S*B*H;
    int* flags = (int*)(tywb + (size_t)S*B*H);

    if (ws_size >= need_persist) {
        prep_kernel<<<(5*MSZ + 255)/256, 256, 0, stream>>>(U, W, Bsw);
        proj0b_kernel<<<2*S*B/ROWSP, 256, 0, stream>>>(src, trg, W, sxwb, tywb);
        zeroflags_kernel<<<(nflags + 255)/256, 256, 0, stream>>>(flags, nflags);
        grid_kernel<<<64, 1024, 0, stream>>>(Bsw, sxwb, tywb, b, out, flags);
        return;
    }

    // -------- staged fallback --------
    prep_kernel<<<(5*MSZ + 255)/256, 256, 0, stream>>>(U, W, Bsw);
    proj0b_kernel<<<2*S*B/ROWSP, 256, 0, stream>>>(src, trg, W, sxwb, tywb);
    for (int v = 0; v < S + T; ++v) {
        int ilo0 = (v > T-1) ? v-(T-1) : 0, ihi0 = (v < S-1) ? v : S-1;
        int n0 = (v <= S+T-2) ? (ihi0 - ilo0 + 1) : 0;
        if (n0 < 0) n0 = 0;
        int n1 = 0;
        int w1 = v - 1;
        if (w1 >= 0) {
            int ilo1 = (w1 > T-1) ? w1-(T-1) : 0, ihi1 = (w1 < S-1) ? w1 : S-1;
            n1 = ihi1 - ilo1 + 1;
        }
        stage_kernel<<<4*(n0+n1), 64, 0, stream>>>(Bsw, sxwb, tywb, b, out, v);
    }
}

// Round 6
// 1356.974 us; speedup vs baseline: 2.2247x; 2.2247x over previous
//
#include <hip/hip_runtime.h>
#include <math.h>

#define S 32
#define T 32
#define B 64
#define H 256
#define MSZ 65536   // elements per swizzled bf16 matrix [8 kt][256 col][32 kk]
#define ROWSP 16

typedef __attribute__((ext_vector_type(8))) short s16x8;
typedef __attribute__((ext_vector_type(4))) float f32x4;

__device__ inline unsigned short f2b(float f){
    unsigned u = __builtin_bit_cast(unsigned, f);
    u += 0x7fffu + ((u >> 16) & 1u);          // RNE
    return (unsigned short)(u >> 16);
}
__device__ inline float b2f(unsigned short s){
    unsigned u = ((unsigned)s) << 16;
    return __builtin_bit_cast(float, u);
}
__device__ inline float tanh_fast(float x){
    float e = __builtin_amdgcn_exp2f(x * 2.8853900817779268f);
    float r = __builtin_amdgcn_rcpf(e + 1.0f);
    return fmaf(-2.0f, r, 1.0f);
}
// executed by a whole wave (uniform address): wait until word != 0
__device__ inline void pollone(const int* f){
    while (__hip_atomic_load(f, __ATOMIC_RELAXED, __HIP_MEMORY_SCOPE_AGENT) == 0)
        __builtin_amdgcn_s_sleep(1);
    asm volatile("" ::: "memory");
}
// wait until both 32-bit words of the 8-byte pair are nonzero
__device__ inline void pollboth(const long long* f){
    for (;;) {
        long long v = __hip_atomic_load(f, __ATOMIC_RELAXED, __HIP_MEMORY_SCOPE_AGENT);
        if (((int)v != 0) && ((int)(v >> 32) != 0)) break;
        __builtin_amdgcn_s_sleep(1);
    }
    asm volatile("" ::: "memory");
}
// A fragment for mfma_f32_16x16x32_bf16 from row-major f32: lane holds A[arow][k0..k0+7]
__device__ inline s16x8 make_afrag(const float* __restrict__ M, int arow, int k0){
    const float* p = M + arow * H + k0;
    float4 x = *(const float4*)(p);
    float4 y = *(const float4*)(p + 4);
    s16x8 r;
    r[0]=(short)f2b(x.x); r[1]=(short)f2b(x.y); r[2]=(short)f2b(x.z); r[3]=(short)f2b(x.w);
    r[4]=(short)f2b(y.x); r[5]=(short)f2b(y.y); r[6]=(short)f2b(y.z); r[7]=(short)f2b(y.w);
    return r;
}

// ---------------- prep: swizzle U (both depths, top/left) + W[1] to bf16 ----
// Bsw[m][kt][c][kk] = M_m[kt*32+kk][c];  m: 0=U0t 1=U0l 2=U1t 3=U1l 4=W1
__global__ __launch_bounds__(256) void prep_kernel(
    const float* __restrict__ U, const float* __restrict__ W,
    unsigned short* __restrict__ Bsw)
{
    int t = blockIdx.x * 256 + threadIdx.x;
    if (t >= 5 * MSZ) return;
    int m  = t >> 16;
    int r  = t & 65535;
    int kt = r >> 13;
    int r2 = r & 8191;
    int c  = r2 >> 5;
    int kk = r2 & 31;
    int krow = kt * 32 + kk;
    float v;
    if (m < 4){ int d = m >> 1, ope = m & 1; v = U[((size_t)d*2*H + ope*H + krow)*H + c]; }
    else      { v = W[((size_t)H + krow)*H + c]; }   // W[1]
    Bsw[t] = f2b(v);
}

// ---------------- depth-0 projections (bf16 out): sxw = src@W0, tyw = trg@W0
__global__ __launch_bounds__(256) void proj0b_kernel(
    const float* __restrict__ src, const float* __restrict__ trg,
    const float* __restrict__ W0, unsigned short* __restrict__ sxw,
    unsigned short* __restrict__ tyw)
{
    const int c = threadIdx.x;
    int gr0 = blockIdx.x * ROWSP;
    const float* inp; unsigned short* outp; int r0;
    if (gr0 < S * B) { inp = src; outp = sxw; r0 = gr0; }
    else             { inp = trg; outp = tyw; r0 = gr0 - S * B; }

    float acc[ROWSP];
#pragma unroll
    for (int rr = 0; rr < ROWSP; ++rr) acc[rr] = 0.f;
    for (int k = 0; k < H; ++k) {
        float wv = W0[k * H + c];
#pragma unroll
        for (int rr = 0; rr < ROWSP; ++rr)
            acc[rr] = fmaf(inp[(size_t)(r0 + rr) * H + k], wv, acc[rr]);
    }
#pragma unroll
    for (int rr = 0; rr < ROWSP; ++rr)
        outp[(size_t)(r0 + rr) * H + c] = f2b(acc[rr]);
}

__global__ __launch_bounds__(256) void zeroflags_kernel(int* flags, int n){
    int t = blockIdx.x * 256 + threadIdx.x;
    if (t < n) flags[t] = 0;
}

// ---------------- persistent dataflow grid kernel (r6) ----------------
// 128 blocks x 512 thr: blk 0..63 = depth0 (i=(blk&63)>>1, half=blk&1),
// 64..127 = depth1. Per cell an 8-byte flag pair {half0, half1}; producer
// half stores 1 into its word; consumers poll 8B (or the sibling word).
// LDS 64KB: [0,16K) own-left hx persist (k-chunk ch); [16K,32K) top k<128;
// [32K,48K) top k>=128; [48K,64K) sibling-left half (k-chunk 1-ch).
__global__ __launch_bounds__(512, 2) void grid_kernel(
    const unsigned short* __restrict__ Bsw,
    const unsigned short* __restrict__ sxwb,
    const unsigned short* __restrict__ tywb,
    const float* __restrict__ bvec,
    float* __restrict__ out,
    int* __restrict__ flags)
{
    __shared__ char lds[65536];

    const int blk   = blockIdx.x;
    const int depth = blk >> 6;
    const int i     = (blk & 63) >> 1;
    const int ch    = blk & 1;

    const int tid  = threadIdx.x;
    const int lane = tid & 63;
    const int wv   = tid >> 6;          // wave 0..7, owns 16 cols
    const int colq = lane & 15;
    const int hi   = lane >> 4;
    const int kk0  = hi * 8;
    const int colw = wv * 16 + colq;    // col within half, 0..127
    const int col  = ch * 128 + colw;   // global col 0..255
    const int hi16 = hi * 16;
    const int lswz = (colq & 7) << 4;   // A-frag read swizzle (A-row&7 == colq&7)

    const int srow = tid >> 3;          // staging row 0..63
    const int k4b  = (tid & 7) * 4;     // staging float4 index within 128-col chunk
    const int swzS = (srow & 7) << 4;

    int* f0w = flags;                   // [S*T][2]
    int* f1w = flags + 2 * S * T;

    const size_t CH_ = (size_t)B * H;
#define OPTR(dd,ii,jj,cc) (out + ((((size_t)(dd)*S + (ii))*T + (jj))*2 + (cc)) * CH_)

#define LOADC(Lp, SP, KC) do { \
    const float* _p = (SP) + (size_t)srow * H + (KC)*128 + k4b*4; \
    (Lp)[0] = *(const float4*)(_p);      (Lp)[1] = *(const float4*)(_p + 4); \
    (Lp)[2] = *(const float4*)(_p + 8);  (Lp)[3] = *(const float4*)(_p + 12); } while(0)

#define WRITEC(BASE, Lp) do { \
    _Pragma("unroll") \
    for (int _l = 0; _l < 4; ++_l) { \
        float4 _v = (Lp)[_l]; uint2 _u; \
        _u.x = f2b(_v.x) | ((unsigned)f2b(_v.y) << 16); \
        _u.y = f2b(_v.z) | ((unsigned)f2b(_v.w) << 16); \
        *(uint2*)(lds + (BASE) + srow*256 + (((k4b + _l)*8) ^ swzS)) = _u; \
    } } while(0)

#define AFRAG(BASE, RT, KTL) (*(const s16x8*)(lds + (BASE) + ((RT)*16 + colq)*256 + ((((KTL)*64) + hi16) ^ lswz)))

    if (depth == 0) {
        s16x8 bfT[8], bfL[8];
#pragma unroll
        for (int kt = 0; kt < 8; ++kt) {
            int o = (kt * H + col) * 32 + kk0;
            bfT[kt] = *(const s16x8*)(Bsw + o);
            bfL[kt] = *(const s16x8*)(Bsw + (size_t)MSZ + o);
        }
        const float bb = bvec[col];
        unsigned short xwr[16];
        {
            const unsigned short* xwp = sxwb + (size_t)i * CH_;
#pragma unroll
            for (int rt = 0; rt < 4; ++rt)
#pragma unroll
                for (int q = 0; q < 4; ++q)
                    xwr[rt*4+q] = xwp[(size_t)(rt*16 + hi*4 + q) * H + col];
        }

        for (int j = 0; j < T; ++j) {
            unsigned short ywr[16];
            {
                const unsigned short* ywp = tywb + (size_t)j * CH_;
#pragma unroll
                for (int rt = 0; rt < 4; ++rt)
#pragma unroll
                    for (int q = 0; q < 4; ++q)
                        ywr[rt*4+q] = ywp[(size_t)(rt*16 + hi*4 + q) * H + col];
            }

            f32x4 acc[4];
#pragma unroll
            for (int rt = 0; rt < 4; ++rt) acc[rt] = (f32x4)(0.f);

            // phase A: own-left MFMAs from persistent LDS (no cross-block wait)
            if (j > 0) {
#pragma unroll
                for (int ktl = 0; ktl < 4; ++ktl)
#pragma unroll
                    for (int rt = 0; rt < 4; ++rt)
                        acc[rt] = __builtin_amdgcn_mfma_f32_16x16x32_bf16(AFRAG(0, rt, ktl), bfL[4*ch + ktl], acc[rt], 0, 0, 0);
                // sibling-left half: per-wave poll + stage
                pollone(&f0w[(i*T + j-1)*2 + (1 - ch)]);
                float4 Ls[4];
                LOADC(Ls, OPTR(0, i, j-1, 0), 1 - ch);
                WRITEC(49152, Ls);
            }
            if (i > 0) {
                pollboth((const long long*)&f0w[((i-1)*T + j)*2]);
                float4 Lt0[4], Lt1[4];
                LOADC(Lt0, OPTR(0, i-1, j, 0), 0);
                LOADC(Lt1, OPTR(0, i-1, j, 0), 1);
                WRITEC(16384, Lt0);
                WRITEC(32768, Lt1);
            }
            __syncthreads();   // B1: staging visible

            // phase B
            if (i > 0) {
#pragma unroll
                for (int kt = 0; kt < 8; ++kt) {
                    const int base = (kt < 4) ? 16384 : 32768;
#pragma unroll
                    for (int rt = 0; rt < 4; ++rt)
                        acc[rt] = __builtin_amdgcn_mfma_f32_16x16x32_bf16(AFRAG(base, rt, kt & 3), bfT[kt], acc[rt], 0, 0, 0);
                }
            }
            if (j > 0) {
#pragma unroll
                for (int ktl = 0; ktl < 4; ++ktl)
#pragma unroll
                    for (int rt = 0; rt < 4; ++rt)
                        acc[rt] = __builtin_amdgcn_mfma_f32_16x16x32_bf16(AFRAG(49152, rt, ktl), bfL[4*(1-ch) + ktl], acc[rt], 0, 0, 0);
            }

            // epilogue: hx + hy (both consumed downstream), LDS own-left update
            float* ox = OPTR(0, i, j, 0);
            float* oy = OPTR(0, i, j, 1);
#pragma unroll
            for (int rt = 0; rt < 4; ++rt)
#pragma unroll
                for (int q = 0; q < 4; ++q) {
                    int idx = rt*4 + q;
                    int r = rt*16 + hi*4 + q;
                    float rec = acc[rt][q] + bb;
                    float hx = tanh_fast(b2f(xwr[idx]) + rec);
                    float hy = tanh_fast(b2f(ywr[idx]) + rec);
                    __hip_atomic_store(&ox[r*H + col], hx, __ATOMIC_RELAXED, __HIP_MEMORY_SCOPE_AGENT);
                    __hip_atomic_store(&oy[r*H + col], hy, __ATOMIC_RELAXED, __HIP_MEMORY_SCOPE_AGENT);
                    *(unsigned short*)(lds + r*256 + ((colw*2) ^ ((r & 7) << 4))) = f2b(hx);
                }
            asm volatile("s_waitcnt vmcnt(0)" ::: "memory");
            __syncthreads();   // B2: all stores drained
            if (tid == 0)
                __hip_atomic_store(&f0w[(i*T + j)*2 + ch], 1, __ATOMIC_RELAXED, __HIP_MEMORY_SCOPE_AGENT);
        }
    } else {
        s16x8 bfT[8], bfL[8];
#pragma unroll
        for (int kt = 0; kt < 8; ++kt) {
            int o = (kt * H + col) * 32 + kk0;
            bfT[kt] = *(const s16x8*)(Bsw + (size_t)2*MSZ + o);
            bfL[kt] = *(const s16x8*)(Bsw + (size_t)3*MSZ + o);
        }
        const float bb = bvec[H + col];

        for (int j = 0; j < T; ++j) {
            // phase A1: depth-0 inputs (d0 runs ahead -> poll is ~free)
            pollboth((const long long*)&f0w[(i*T + j)*2]);
            const float* hx0 = OPTR(0, i, j, 0);
            const float* hy0 = OPTR(0, i, j, 1);

            // stream W1 B-frags (opaque base defeats LICM -> no VGPR blowup)
            uintptr_t bsw_o = (uintptr_t)Bsw;
            asm volatile("" : "+v"(bsw_o));
            const unsigned short* mW = (const unsigned short*)bsw_o + (size_t)4*MSZ;

            f32x4 ar[4], ax[4], ay[4];
#pragma unroll
            for (int rt = 0; rt < 4; ++rt){ ar[rt]=(f32x4)(0.f); ax[rt]=(f32x4)(0.f); ay[rt]=(f32x4)(0.f); }

#pragma unroll
            for (int kt = 0; kt < 8; ++kt) {
                s16x8 bW = *(const s16x8*)(mW + (kt * H + col) * 32 + kk0);
                const int k0 = kt*32 + kk0;
#pragma unroll
                for (int rt = 0; rt < 4; ++rt) {
                    ax[rt] = __builtin_amdgcn_mfma_f32_16x16x32_bf16(make_afrag(hx0, rt*16 + colq, k0), bW, ax[rt], 0, 0, 0);
                    ay[rt] = __builtin_amdgcn_mfma_f32_16x16x32_bf16(make_afrag(hy0, rt*16 + colq, k0), bW, ay[rt], 0, 0, 0);
                }
            }

            // phase A2: own-left from persistent LDS; sibling + top staging
            if (j > 0) {
#pragma unroll
                for (int ktl = 0; ktl < 4; ++ktl)
#pragma unroll
                    for (int rt = 0; rt < 4; ++rt)
                        ar[rt] = __builtin_amdgcn_mfma_f32_16x16x32_bf16(AFRAG(0, rt, ktl), bfL[4*ch + ktl], ar[rt], 0, 0, 0);
                pollone(&f1w[(i*T + j-1)*2 + (1 - ch)]);
                float4 Ls[4];
                LOADC(Ls, OPTR(1, i, j-1, 0), 1 - ch);
                WRITEC(49152, Ls);
            }
            if (i > 0) {
                pollboth((const long long*)&f1w[((i-1)*T + j)*2]);
                float4 Lt0[4], Lt1[4];
                LOADC(Lt0, OPTR(1, i-1, j, 0), 0);
                LOADC(Lt1, OPTR(1, i-1, j, 0), 1);
                WRITEC(16384, Lt0);
                WRITEC(32768, Lt1);
            }
            __syncthreads();   // B1

            if (i > 0) {
#pragma unroll
                for (int kt = 0; kt < 8; ++kt) {
                    const int base = (kt < 4) ? 16384 : 32768;
#pragma unroll
                    for (int rt = 0; rt < 4; ++rt)
                        ar[rt] = __builtin_amdgcn_mfma_f32_16x16x32_bf16(AFRAG(base, rt, kt & 3), bfT[kt], ar[rt], 0, 0, 0);
                }
            }
            if (j > 0) {
#pragma unroll
                for (int ktl = 0; ktl < 4; ++ktl)
#pragma unroll
                    for (int rt = 0; rt < 4; ++rt)
                        ar[rt] = __builtin_amdgcn_mfma_f32_16x16x32_bf16(AFRAG(49152, rt, ktl), bfL[4*(1-ch) + ktl], ar[rt], 0, 0, 0);
            }

            // epilogue: hx1 (consumed) before publish; hy1 (dead end) after
            float recs[16];
            float* ox = OPTR(1, i, j, 0);
#pragma unroll
            for (int rt = 0; rt < 4; ++rt)
#pragma unroll
                for (int q = 0; q < 4; ++q) {
                    int idx = rt*4 + q;
                    int r = rt*16 + hi*4 + q;
                    float rec = ar[rt][q] + bb;
                    recs[idx] = rec;
                    float hx = tanh_fast(ax[rt][q] + rec);
                    __hip_atomic_store(&ox[r*H + col], hx, __ATOMIC_RELAXED, __HIP_MEMORY_SCOPE_AGENT);
                    *(unsigned short*)(lds + r*256 + ((colw*2) ^ ((r & 7) << 4))) = f2b(hx);
                }
            asm volatile("s_waitcnt vmcnt(0)" ::: "memory");
            __syncthreads();   // B2
            if (tid == 0)
                __hip_atomic_store(&f1w[(i*T + j)*2 + ch], 1, __ATOMIC_RELAXED, __HIP_MEMORY_SCOPE_AGENT);

            float* oy = OPTR(1, i, j, 1);
#pragma unroll
            for (int rt = 0; rt < 4; ++rt)
#pragma unroll
                for (int q = 0; q < 4; ++q) {
                    int r = rt*16 + hi*4 + q;
                    float hy = tanh_fast(ay[rt][q] + recs[rt*4 + q]);
                    __hip_atomic_store(&oy[r*H + col], hy, __ATOMIC_RELAXED, __HIP_MEMORY_SCOPE_AGENT);
                }
        }
    }
#undef OPTR
#undef LOADC
#undef WRITEC
#undef AFRAG
}

// =================== staged fallback (round-2 structure) ===================
__global__ __launch_bounds__(64) void stage_kernel(
    const unsigned short* __restrict__ Bsw,
    const unsigned short* __restrict__ sxwb,
    const unsigned short* __restrict__ tywb,
    const float* __restrict__ bvec,
    float* __restrict__ out, int v)
{
    const int lane = threadIdx.x;
    const int cellid = blockIdx.x >> 2;
    const int stripe = blockIdx.x & 3;

    int ilo0 = (v > T-1) ? v-(T-1) : 0, ihi0 = (v < S-1) ? v : S-1;
    int n0 = (v <= S+T-2) ? (ihi0 - ilo0 + 1) : 0;
    if (n0 < 0) n0 = 0;
    int w1 = v - 1;
    int ilo1 = (w1 > T-1) ? w1-(T-1) : 0;

    int d, i, j;
    if (cellid < n0) { d = 0; i = ilo0 + cellid; j = v - i; }
    else             { d = 1; int q = cellid - n0; i = ilo1 + q; j = w1 - i; }

    const int r0   = stripe * 16;
    const int arow = r0 + (lane & 15);
    const int kk0  = (lane >> 4) * 8;
    const int colq = lane & 15;
    const int rowq = r0 + ((lane >> 4) << 2);

#define OUTB(dd,ii,jj,cc) (out + ((((size_t)(dd)*S + (ii))*T + (jj))*2 + (cc)) * (size_t)(B*H))

    if (d == 0) {
        f32x4 acc[16];
#pragma unroll
        for (int t = 0; t < 16; ++t) acc[t] = (f32x4)(0.f);
        if (i > 0) {
            const float* topM = OUTB(0, i-1, j, 0);
            const unsigned short* Bt = Bsw + 0*MSZ;
            for (int kt = 0; kt < 8; ++kt) {
                s16x8 a = make_afrag(topM, arow, kt*32 + kk0);
                const unsigned short* bp = Bt + (kt*H + colq)*32 + kk0;
#pragma unroll
                for (int ct = 0; ct < 16; ++ct)
                    acc[ct] = __builtin_amdgcn_mfma_f32_16x16x32_bf16(a, *(const s16x8*)(bp + ct*512), acc[ct], 0, 0, 0);
            }
        }
        if (j > 0) {
            const float* lftM = OUTB(0, i, j-1, 0);
            const unsigned short* Bl = Bsw + 1*MSZ;
            for (int kt = 0; kt < 8; ++kt) {
                s16x8 a = make_afrag(lftM, arow, kt*32 + kk0);
                const unsigned short* bp = Bl + (kt*H + colq)*32 + kk0;
#pragma unroll
                for (int ct = 0; ct < 16; ++ct)
                    acc[ct] = __builtin_amdgcn_mfma_f32_16x16x32_bf16(a, *(const s16x8*)(bp + ct*512), acc[ct], 0, 0, 0);
            }
        }
        const unsigned short* xwp = sxwb + (size_t)i * B * H;
        const unsigned short* ywp = tywb + (size_t)j * B * H;
        float* ox = OUTB(0, i, j, 0);
        float* oy = OUTB(0, i, j, 1);
#pragma unroll
        for (int ct = 0; ct < 16; ++ct) {
            int col = ct*16 + colq;
            float bc = bvec[col];
#pragma unroll
            for (int q = 0; q < 4; ++q) {
                int row = rowq + q;
                float rec = acc[ct][q] + bc;
                ox[row*H + col] = tanh_fast(b2f(xwp[row*H + col]) + rec);
                oy[row*H + col] = tanh_fast(b2f(ywp[row*H + col]) + rec);
            }
        }
    } else {
        const float* hx0 = OUTB(0, i, j, 0);
        const float* hy0 = OUTB(0, i, j, 1);
        const float* topM = (i > 0) ? OUTB(1, i-1, j, 0) : (const float*)0;
        const float* lftM = (j > 0) ? OUTB(1, i, j-1, 0) : (const float*)0;
        const unsigned short* BU1t = Bsw + 2*MSZ;
        const unsigned short* BU1l = Bsw + 3*MSZ;
        const unsigned short* BW1  = Bsw + 4*MSZ;
        float* ox = OUTB(1, i, j, 0);
        float* oy = OUTB(1, i, j, 1);

        for (int halfc = 0; halfc < 2; ++halfc) {
            f32x4 arr[8], axx[8], ayy[8];
#pragma unroll
            for (int t = 0; t < 8; ++t) { arr[t]=(f32x4)(0.f); axx[t]=(f32x4)(0.f); ayy[t]=(f32x4)(0.f); }
            const int bbase = halfc*4096 + colq*32 + kk0;

            for (int kt = 0; kt < 8; ++kt) {
                const int k0 = kt*32 + kk0;
                const int bofs = kt*H*32 + bbase;
                if (topM) {
                    s16x8 a = make_afrag(topM, arow, k0);
#pragma unroll
                    for (int ct = 0; ct < 8; ++ct)
                        arr[ct] = __builtin_amdgcn_mfma_f32_16x16x32_bf16(a, *(const s16x8*)(BU1t + bofs + ct*512), arr[ct], 0, 0, 0);
                }
                if (lftM) {
                    s16x8 a = make_afrag(lftM, arow, k0);
#pragma unroll
                    for (int ct = 0; ct < 8; ++ct)
                        arr[ct] = __builtin_amdgcn_mfma_f32_16x16x32_bf16(a, *(const s16x8*)(BU1l + bofs + ct*512), arr[ct], 0, 0, 0);
                }
                {
                    s16x8 a = make_afrag(hx0, arow, k0);
#pragma unroll
                    for (int ct = 0; ct < 8; ++ct)
                        axx[ct] = __builtin_amdgcn_mfma_f32_16x16x32_bf16(a, *(const s16x8*)(BW1 + bofs + ct*512), axx[ct], 0, 0, 0);
                }
                {
                    s16x8 a = make_afrag(hy0, arow, k0);
#pragma unroll
                    for (int ct = 0; ct < 8; ++ct)
                        ayy[ct] = __builtin_amdgcn_mfma_f32_16x16x32_bf16(a, *(const s16x8*)(BW1 + bofs + ct*512), ayy[ct], 0, 0, 0);
                }
            }
#pragma unroll
            for (int ct = 0; ct < 8; ++ct) {
                int col = halfc*128 + ct*16 + colq;
                float bc = bvec[H + col];
#pragma unroll
                for (int q = 0; q < 4; ++q) {
                    int row = rowq + q;
                    float rec = arr[ct][q] + bc;
                    ox[row*H + col] = tanh_fast(axx[ct][q] + rec);
                    oy[row*H + col] = tanh_fast(ayy[ct][q] + rec);
                }
            }
        }
    }
#undef OUTB
}

// ============================ host launcher ================================
extern "C" void kernel_launch(void* const* d_in, const int* in_sizes, int n_in,
                              void* d_out, int out_size, void* d_ws, size_t ws_size,
                              hipStream_t stream)
{
    const float* src = (const float*)d_in[0];
    const float* trg = (const float*)d_in[1];
    const float* W   = (const float*)d_in[2];
    const float* U   = (const float*)d_in[3];
    const float* b   = (const float*)d_in[4];
    float* out = (float*)d_out;

    const int nflags = 4 * S * T;   // 2 depths x S*T cells x 2 words
    const size_t need_stage   = (size_t)5*MSZ*2 + (size_t)2*S*B*H*2;
    const size_t need_persist = need_stage + (size_t)nflags*sizeof(int);

    unsigned short* Bsw  = (unsigned short*)d_ws;
    unsigned short* sxwb = Bsw + (size_t)5*MSZ;
    unsigned short* tywb = sxwb + (size_t)S*B*H;
    int* flags = (int*)(tywb + (size_t)S*B*H);

    if (ws_size >= need_persist) {
        prep_kernel<<<(5*MSZ + 255)/256, 256, 0, stream>>>(U, W, Bsw);
        proj0b_kernel<<<2*S*B/ROWSP, 256, 0, stream>>>(src, trg, W, sxwb, tywb);
        zeroflags_kernel<<<(nflags + 255)/256, 256, 0, stream>>>(flags, nflags);
        grid_kernel<<<128, 512, 0, stream>>>(Bsw, sxwb, tywb, b, out, flags);
        return;
    }

    // -------- staged fallback --------
    prep_kernel<<<(5*MSZ + 255)/256, 256, 0, stream>>>(U, W, Bsw);
    proj0b_kernel<<<2*S*B/ROWSP, 256, 0, stream>>>(src, trg, W, sxwb, tywb);
    for (int v = 0; v < S + T; ++v) {
        int ilo0 = (v > T-1) ? v-(T-1) : 0, ihi0 = (v < S-1) ? v : S-1;
        int n0 = (v <= S+T-2) ? (ihi0 - ilo0 + 1) : 0;
        if (n0 < 0) n0 = 0;
        int n1 = 0;
        int w1 = v - 1;
        if (w1 >= 0) {
            int ilo1 = (w1 > T-1) ? w1-(T-1) : 0, ihi1 = (w1 < S-1) ? w1 : S-1;
            n1 = ihi1 - ilo1 + 1;
        }
        stage_kernel<<<4*(n0+n1), 64, 0, stream>>>(Bsw, sxwb, tywb, b, out, v);
    }
}